// Round 11
// baseline (327.087 us; speedup 1.0000x reference)
//
#include <hip/hip_runtime.h>

static constexpr int Tn = 2000;
static constexpr int Bn = 512;
static constexpr int Cn = 29;
static constexpr int Ln = 150;
static constexpr float LOG2E_F = 1.4426950408889634f;
static constexpr float LN2_F   = 0.6931471805599453f;
static constexpr float NEGV    = -1e30f;

// workspace layout (floats)
static constexpr int WS_DEN_F = 0;                      // 512 (log2-domain log_den per b)
static constexpr int WS_NUM_F = 2 * 512 * 32;           // 512*160
static constexpr int WS_NUM_B = 2 * 512 * 32 + 512 * 160;

static constexpr int NSEG = 8;                          // den segments per batch
static constexpr int SEGL = 250;                        // steps per segment (last: 249)

typedef float  f32x16 __attribute__((ext_vector_type(16)));
typedef float  f32x4  __attribute__((ext_vector_type(4)));
typedef __bf16 bf16x8 __attribute__((ext_vector_type(8)));
typedef unsigned int u32x4 __attribute__((ext_vector_type(4)));

#if __has_builtin(__builtin_amdgcn_exp2f)
#define FEXP2(x) __builtin_amdgcn_exp2f(x)
#else
#define FEXP2(x) exp2f(x)
#endif
#if __has_builtin(__builtin_amdgcn_logf)
#define FLOG2(x) __builtin_amdgcn_logf(x)
#else
#define FLOG2(x) log2f(x)
#endif

__device__ __forceinline__ int exp_of(float x) {           // floor(log2(x)), x normal >0
    return ((__float_as_int(x) >> 23) & 255) - 127;
}
__device__ __forceinline__ float pow2i(int e) {            // 2^e, e in [-126,127]
    return __int_as_float((e + 127) << 23);
}
__device__ __forceinline__ unsigned short f2bf_rne(float x) {
    unsigned u = __float_as_uint(x);
    u += 0x7fffu + ((u >> 16) & 1u);
    return (unsigned short)(u >> 16);
}
__device__ __forceinline__ unsigned cvtpk_bf16(float lo, float hi) {
    unsigned r;
    asm("v_cvt_pk_bf16_f32 %0, %1, %2" : "=v"(r) : "v"(lo), "v"(hi));
    return r;
}
__device__ __forceinline__ void xswap32(unsigned &a, unsigned &b) {
#if __has_builtin(__builtin_amdgcn_permlane32_swap)
    auto r = __builtin_amdgcn_permlane32_swap(a, b, false, false);
    a = r[0]; b = r[1];
#else
    unsigned pa = (unsigned)__shfl_xor((int)a, 32);
    unsigned pb = (unsigned)__shfl_xor((int)b, 32);
    bool hb = (threadIdx.x & 32) != 0;
    unsigned na = hb ? pb : a;
    unsigned nb = hb ? b : pa;
    a = na; b = nb;
#endif
}
// D-layout f32[16] -> B-operand fragments (validated r4-r10)
__device__ __forceinline__ void packDtoB(const float* W, bf16x8 &B1, bf16x8 &B2) {
    unsigned pk[8];
#pragma unroll
    for (int q = 0; q < 8; ++q) pk[q] = cvtpk_bf16(W[2 * q], W[2 * q + 1]);
    xswap32(pk[0], pk[2]); xswap32(pk[1], pk[3]);
    xswap32(pk[4], pk[6]); xswap32(pk[5], pk[7]);
    B1 = __builtin_bit_cast(bf16x8, u32x4{pk[0], pk[1], pk[2], pk[3]});
    B2 = __builtin_bit_cast(bf16x8, u32x4{pk[4], pk[5], pk[6], pk[7]});
}
__device__ __forceinline__ void renorm16(float* W, float &Sacc) {
    float m = W[0];
#pragma unroll
    for (int r = 1; r < 16; ++r) m = fmaxf(m, W[r]);
#pragma unroll
    for (int sh = 1; sh <= 32; sh <<= 1) m = fmaxf(m, __shfl_xor(m, sh));
    int g = exp_of(m);
    float iv = pow2i(-g);
#pragma unroll
    for (int r = 0; r < 16; ++r) W[r] *= iv;
    Sacc += (float)g;
}

__global__ __launch_bounds__(512)
void asg_scan(const float* __restrict__ inp, const float* __restrict__ tr,
              const int* __restrict__ tg, float* __restrict__ ws)
{
    const int tid = threadIdx.x;
    const int bid = blockIdx.x;

    // bf16-packed segment matrices: am[seg][row][colpair] = bf(row,2c)|bf(row,2c+1)<<16
    __shared__ unsigned am[NSEG][32][20];     // 20 words/row: 16B-aligned b128 reads
    __shared__ float uring[NSEG][8][32];
    __shared__ float scl[NSEG];

    if (bid < 512) {
        // ============ DENOMINATOR: 8 segment transfer matrices / batch =======
        const int lane = tid & 63;
        const int wid  = tid >> 6;           // 0..7 = segment
        const int col  = lane & 31;
        const int hi   = lane >> 5;
        const int b    = bid;
        const size_t BC = (size_t)Bn * Cn;

        // E in bf16 A-fragments (validated r4)
        unsigned aw[8];
#pragma unroll
        for (int p = 0; p < 8; ++p) {
            int kb = (p >> 2) * 16 + 8 * hi + (p & 3) * 2;
            unsigned short lo = 0, hh = 0;
            if (col < Cn) {
                if (kb < Cn)     lo = f2bf_rne(FEXP2(LOG2E_F * tr[(1 + col) * Cn + kb]));
                if (kb + 1 < Cn) hh = f2bf_rne(FEXP2(LOG2E_F * tr[(1 + col) * Cn + kb + 1]));
            }
            aw[p] = (unsigned)lo | ((unsigned)hh << 16);
        }
        const bf16x8 A1 = __builtin_bit_cast(bf16x8, u32x4{aw[0], aw[1], aw[2], aw[3]});
        const bf16x8 A2 = __builtin_bit_cast(bf16x8, u32x4{aw[4], aw[5], aw[6], aw[7]});

        f32x16 z;
#pragma unroll
        for (int r = 0; r < 16; ++r) z[r] = 0.f;

        const int start = 1 + SEGL * wid;
        const int cnt   = min(SEGL, Tn - start);           // 250 ... 249

        const float* ebase = inp + (size_t)b * Cn + min(col, Cn - 1);

        // 3-stage raw pipeline: er = raws steps s+2..s+9 (conversion sources this
        // block), er2 = s+10..s+17; nl loaded during block for s+18..s+25.
        {
            float r0 = ebase[(size_t)(start)     * BC];
            float r1 = ebase[(size_t)(start + 1) * BC];
            if (lane < 32) {
                uring[wid][0][col] = FEXP2(LOG2E_F * r0);
                uring[wid][1][col] = FEXP2(LOG2E_F * r1);
            }
        }
        float er[8], er2[8];
#pragma unroll
        for (int u = 0; u < 8; ++u) er[u]  = ebase[(size_t)(start + 2 + u) * BC];
#pragma unroll
        for (int u = 0; u < 8; ++u) er2[u] = ebase[(size_t)(start + 10 + u) * BC];

        float W[16];                                       // M in D-layout, init I
#pragma unroll
        for (int r = 0; r < 16; ++r) {
            int row = (r & 3) + 8 * (r >> 2) + 4 * hi;
            W[r] = (row == col) ? 1.0f : 0.0f;
        }
        float Sacc = 0.f;

        int s = 0;
        for (; s + 8 <= cnt; s += 8) {
            float nl[8];
#pragma unroll
            for (int u = 0; u < 8; ++u) {
                nl[u] = ebase[(size_t)min(start + s + 18 + u, Tn - 1) * BC];
                float un = FEXP2(LOG2E_F * er[u]);          // step s+u+2
                if (lane < 32) uring[wid][(u + 2) & 7][col] = un;
                f32x4 uu0 = *(const f32x4*)&uring[wid][u][4 * hi];
                f32x4 uu1 = *(const f32x4*)&uring[wid][u][8 + 4 * hi];
                f32x4 uu2 = *(const f32x4*)&uring[wid][u][16 + 4 * hi];
                f32x4 uu3 = *(const f32x4*)&uring[wid][u][24 + 4 * hi];
                bf16x8 B1, B2;
                packDtoB(W, B1, B2);
                f32x16 d = __builtin_amdgcn_mfma_f32_32x32x16_bf16(A1, B1, z, 0, 0, 0);
                d = __builtin_amdgcn_mfma_f32_32x32x16_bf16(A2, B2, d, 0, 0, 0);
#pragma unroll
                for (int r = 0; r < 16; ++r) {
                    f32x4 uq = (r < 4) ? uu0 : (r < 8) ? uu1 : (r < 12) ? uu2 : uu3;
                    W[r] = d[r] * uq[r & 3];
                }
                if (u == 7) renorm16(W, Sacc);
            }
#pragma unroll
            for (int u = 0; u < 8; ++u) { er[u] = er2[u]; er2[u] = nl[u]; }
        }
        {   // tail: rem = 2 (segs 0-6) or 1 (seg 7); uring slots 0,1 hold s, s+1
            const int rem = cnt - s;
#pragma unroll
            for (int u = 0; u < 2; ++u) {
                if (u < rem) {
                    f32x4 uu0 = *(const f32x4*)&uring[wid][u][4 * hi];
                    f32x4 uu1 = *(const f32x4*)&uring[wid][u][8 + 4 * hi];
                    f32x4 uu2 = *(const f32x4*)&uring[wid][u][16 + 4 * hi];
                    f32x4 uu3 = *(const f32x4*)&uring[wid][u][24 + 4 * hi];
                    bf16x8 B1, B2;
                    packDtoB(W, B1, B2);
                    f32x16 d = __builtin_amdgcn_mfma_f32_32x32x16_bf16(A1, B1, z, 0, 0, 0);
                    d = __builtin_amdgcn_mfma_f32_32x32x16_bf16(A2, B2, d, 0, 0, 0);
#pragma unroll
                    for (int r = 0; r < 16; ++r) {
                        f32x4 uq = (r < 4) ? uu0 : (r < 8) ? uu1 : (r < 12) ? uu2 : uu3;
                        W[r] = d[r] * uq[r & 3];
                    }
                }
            }
            renorm16(W, Sacc);
        }

        // store P_w as packed bf16 (u16 element writes)
        {
            unsigned short* s16 = (unsigned short*)am[wid];
#pragma unroll
            for (int r = 0; r < 16; ++r) {
                int row = (r & 3) + 8 * (r >> 2) + 4 * hi;
                s16[row * 40 + col] = f2bf_rne(W[r]);
            }
        }
        if (lane == 0) scl[wid] = Sacc;
        __syncthreads();

        // LDS matrix pair product (bf16 storage): out(D-layout regs) = am[Ls] x am[Rs]
        auto lds_mul = [&](int Ls, int Rs, float* Wo) {
            u32x4 a0 = *(const u32x4*)&am[Ls][col][4 * hi];
            u32x4 a1 = *(const u32x4*)&am[Ls][col][8 + 4 * hi];
            bf16x8 LA1 = __builtin_bit_cast(bf16x8, a0);
            bf16x8 LA2 = __builtin_bit_cast(bf16x8, a1);
            const unsigned short* r16 = (const unsigned short*)am[Rs];
            unsigned pk[8];
#pragma unroll
            for (int q = 0; q < 8; ++q) {
                int ra = ((2 * q) & 3) + 8 * ((2 * q) >> 2) + 4 * hi;
                pk[q] = (unsigned)r16[ra * 40 + col] |
                        ((unsigned)r16[(ra + 1) * 40 + col] << 16);
            }
            xswap32(pk[0], pk[2]); xswap32(pk[1], pk[3]);
            xswap32(pk[4], pk[6]); xswap32(pk[5], pk[7]);
            bf16x8 B1 = __builtin_bit_cast(bf16x8, u32x4{pk[0], pk[1], pk[2], pk[3]});
            bf16x8 B2 = __builtin_bit_cast(bf16x8, u32x4{pk[4], pk[5], pk[6], pk[7]});
            f32x16 d = __builtin_amdgcn_mfma_f32_32x32x16_bf16(LA1, B1, z, 0, 0, 0);
            d = __builtin_amdgcn_mfma_f32_32x32x16_bf16(LA2, B2, d, 0, 0, 0);
#pragma unroll
            for (int r = 0; r < 16; ++r) Wo[r] = d[r];
        };
        auto store_mat = [&](int slot, const float* Wo) {
            unsigned short* s16 = (unsigned short*)am[slot];
#pragma unroll
            for (int r = 0; r < 16; ++r) {
                int row = (r & 3) + 8 * (r >> 2) + 4 * hi;
                s16[row * 40 + col] = f2bf_rne(Wo[r]);
            }
        };

        // L1: wid<4: am[2w] <- P_{2w+1} x P_{2w}
        if (wid < 4) {
            float Wq[16];
            lds_mul(2 * wid + 1, 2 * wid, Wq);
            float Sg = scl[2 * wid] + scl[2 * wid + 1];
            renorm16(Wq, Sg);
            store_mat(2 * wid, Wq);
            if (lane == 0) scl[2 * wid] = Sg;
        }
        __syncthreads();
        // L2: wid<2: am[4w] <- am[4w+2] x am[4w]
        if (wid < 2) {
            float Wq[16];
            lds_mul(4 * wid + 2, 4 * wid, Wq);
            float Sg = scl[4 * wid] + scl[4 * wid + 2];
            renorm16(Wq, Sg);
            store_mat(4 * wid, Wq);
            if (lane == 0) scl[4 * wid] = Sg;
        }
        __syncthreads();
        // L3 + alpha0 apply (wave 0): R = am[4] x am[0]
        if (wid == 0) {
            float Wq[16];
            lds_mul(4, 0, Wq);
            const float Stot = scl[0] + scl[4];
            float a0v = 0.f;
            if (col < Cn)
                a0v = FEXP2(LOG2E_F * (inp[(size_t)b * Cn + col] + tr[col]));
            float ssum = 0.f;
#pragma unroll
            for (int r = 0; r < 16; ++r) ssum += Wq[r];
            float t = ssum * a0v;
#pragma unroll
            for (int sh = 1; sh <= 32; sh <<= 1) t += __shfl_xor(t, sh);
            if (lane == 0) ws[WS_DEN_F + b] = FLOG2(t) + Stot;
        }
    } else {
        // ==== NUMERATOR: linear, per-lane pow2 scales (r10-validated math),
        //      3-block raw ring ====
        const int nid = (bid - 512) * 8 + (tid >> 6);
        const int dir = nid >> 9;
        const int b   = nid & 511;
        const int k   = tid & 63;
        const int* tb = tg + b * Ln;

        const int l0 = 3 * k, l1 = 3 * k + 1, l2 = 3 * k + 2;
        const int t0i = (l0 < Ln) ? tb[l0] : 0;
        const int t1i = (l1 < Ln) ? tb[l1] : 0;
        const int t2i = (l2 < Ln) ? tb[l2] : 0;
        const float S0 = FEXP2(LOG2E_F * tr[(1 + t0i) * Cn + t0i]);
        const float S1 = FEXP2(LOG2E_F * tr[(1 + t1i) * Cn + t1i]);
        const float S2 = FEXP2(LOG2E_F * tr[(1 + t2i) * Cn + t2i]);
        const float M0 = (l0 >= 1 && l0 < Ln)
                         ? FEXP2(LOG2E_F * tr[(1 + t0i) * Cn + tb[l0 - 1]]) : 0.f;
        const float M1 = (l1 < Ln) ? FEXP2(LOG2E_F * tr[(1 + t1i) * Cn + t0i]) : 0.f;
        const float M2 = (l2 < Ln) ? FEXP2(LOG2E_F * tr[(1 + t2i) * Cn + t1i]) : 0.f;

        float w0 = 0.f, w1 = 0.f, w2 = 0.f;
        if (dir == 0) {
            if (k == 0) w0 = FEXP2(LOG2E_F * (tr[t0i] + inp[(size_t)b * Cn + t0i]));
        } else {
            if (k == 49) w2 = 1.f;
        }
        int   sE  = 0;
        float m0x = M0;
        float fdn = 1.f;
        int   pgx = 0, psp = 0;

        const size_t BC = (size_t)Bn * Cn;
        const int o0 = b * Cn + t0i, o1 = b * Cn + t1i, o2 = b * Cn + t2i;
        const int t0 = dir ? (Tn - 1) : 1;
        const int dt = dir ? -1 : 1;
        const int steps = dir ? 1000 : 999;

        float ue0[4], ue1[4], ue2[4], pr0[4], pr1[4], pr2[4];
#pragma unroll
        for (int u = 0; u < 4; ++u) {          // block 0 converted
            const float* pt = inp + (size_t)(t0 + u * dt) * BC;
            ue0[u] = FEXP2(LOG2E_F * pt[o0]);
            ue1[u] = FEXP2(LOG2E_F * pt[o1]);
            ue2[u] = FEXP2(LOG2E_F * pt[o2]);
        }
#pragma unroll
        for (int u = 0; u < 4; ++u) {          // block 1 raw
            const float* pt = inp + (size_t)(t0 + (4 + u) * dt) * BC;
            pr0[u] = pt[o0]; pr1[u] = pt[o1]; pr2[u] = pt[o2];
        }

        for (int s = 0; s < steps; s += 4) {
            float n0[4], n1[4], n2[4];
#pragma unroll
            for (int u = 0; u < 4; ++u) {      // load block s+8 (in range: see bounds)
                const float* pt = inp + (size_t)(t0 + (s + 8 + u) * dt) * BC;
                n0[u] = pt[o0]; n1[u] = pt[o1]; n2[u] = pt[o2];
            }
#pragma unroll
            for (int u = 0; u < 4; ++u) {
                if (s + u < steps) {
                    if (u == 1) {              // apply pending renorm (measured @u==3)
                        float rs = pow2i(-pgx);
                        w0 *= rs; w1 *= rs; w2 *= rs; sE += pgx;
                        int df = psp - sE;
                        df = max(-126, min(56, df));
                        float fx = pow2i(df);
                        m0x = M0 * fx; fdn = fx;
                    }
                    if (dir == 0) {
                        float sh = __shfl_up(w2, 1);
                        sh = (k == 0) ? 0.f : sh;
                        float nn0 = ue0[u] * fmaf(w0, S0, sh * m0x);
                        float nn1 = ue1[u] * fmaf(w1, S1, w0 * M1);
                        float nn2 = ue2[u] * fmaf(w2, S2, w1 * M2);
                        w0 = nn0; w1 = nn1; w2 = nn2;
                    } else {
                        float q0 = w0 * ue0[u], q1 = w1 * ue1[u], q2 = w2 * ue2[u];
                        float mn = __shfl_down(q0 * M0, 1);
                        w0 = fmaf(q0, S0, q1 * M1);
                        w1 = fmaf(q1, S1, q2 * M2);
                        w2 = fmaf(q2, S2, mn * fdn);
                    }
                    if (u == 3) {
                        float mxn = fmaxf(fmaxf(w0, w1), w2);
                        pgx = (mxn > 0.f) ? exp_of(mxn) : 0;
                        int sp = sE + pgx;
                        psp = dir ? __shfl_down(sp, 1) : __shfl_up(sp, 1);
                    }
                }
            }
#pragma unroll
            for (int u = 0; u < 4; ++u) {      // convert block s+4; shift ring
                ue0[u] = FEXP2(LOG2E_F * pr0[u]);
                ue1[u] = FEXP2(LOG2E_F * pr1[u]);
                ue2[u] = FEXP2(LOG2E_F * pr2[u]);
                pr0[u] = n0[u]; pr1[u] = n1[u]; pr2[u] = n2[u];
            }
        }
        const float fsE = (float)sE;
        const int base = (dir ? WS_NUM_B : WS_NUM_F) + b * 160;
        if (l0 < Ln)     ws[base + l0]     = (w0 > 0.f) ? FLOG2(w0) + fsE : NEGV;
        if (l0 + 1 < Ln) ws[base + l0 + 1] = (w1 > 0.f) ? FLOG2(w1) + fsE : NEGV;
        if (l0 + 2 < Ln) ws[base + l0 + 2] = (w2 > 0.f) ? FLOG2(w2) + fsE : NEGV;
    }
}

__global__ __launch_bounds__(512)
void asg_combine(const float* __restrict__ ws, float* __restrict__ out)
{
    __shared__ float red[512];
    const int b = threadIdx.x;

    const float ld = ws[WS_DEN_F + b];            // log2 domain

    const float* nf = ws + WS_NUM_F + b * 160;
    const float* nb = ws + WS_NUM_B + b * 160;
    float vm2 = -3.0e38f;
    for (int l = 0; l < Ln; ++l) vm2 = fmaxf(vm2, nf[l] + nb[l]);
    float sum2 = 0.f;
    for (int l = 0; l < Ln; ++l) sum2 += FEXP2(nf[l] + nb[l] - vm2);
    float ln = vm2 + FLOG2(sum2);

    red[b] = ld - ln;
    __syncthreads();
    for (int off = 256; off > 0; off >>= 1) {
        if (b < off) red[b] += red[b + off];
        __syncthreads();
    }
    if (b == 0) out[0] = red[0] * (LN2_F / 512.0f);
}

extern "C" void kernel_launch(void* const* d_in, const int* in_sizes, int n_in,
                              void* d_out, int out_size, void* d_ws, size_t ws_size,
                              hipStream_t stream)
{
    const float* inp = (const float*)d_in[0];
    const float* tr  = (const float*)d_in[1];
    const int*   tg  = (const int*)d_in[2];
    float* out = (float*)d_out;
    float* ws  = (float*)d_ws;

    hipLaunchKernelGGL(asg_scan,    dim3(640), dim3(512), 0, stream, inp, tr, tg, ws);
    hipLaunchKernelGGL(asg_combine, dim3(1),   dim3(512), 0, stream, ws, out);
}

// Round 12
// 247.859 us; speedup vs baseline: 1.3196x; 1.3196x over previous
//
#include <hip/hip_runtime.h>

static constexpr int Tn = 2000;
static constexpr int Bn = 512;
static constexpr int Cn = 29;
static constexpr int Ln = 150;
static constexpr float LOG2E_F = 1.4426950408889634f;
static constexpr float LN2_F   = 0.6931471805599453f;
static constexpr float NEGV    = -1e30f;

// workspace layout (floats)
static constexpr int WS_DEN_F = 0;                      // 512 (log2-domain log_den per b)
static constexpr int WS_NUM_F = 2 * 512 * 32;           // 512*160
static constexpr int WS_NUM_B = 2 * 512 * 32 + 512 * 160;

static constexpr int NSEG = 8;                          // den segments per batch
static constexpr int SEGL = 250;                        // steps per segment (last: 249)

typedef float  f32x16 __attribute__((ext_vector_type(16)));
typedef float  f32x4  __attribute__((ext_vector_type(4)));
typedef __bf16 bf16x8 __attribute__((ext_vector_type(8)));
typedef unsigned int u32x4 __attribute__((ext_vector_type(4)));

#if __has_builtin(__builtin_amdgcn_exp2f)
#define FEXP2(x) __builtin_amdgcn_exp2f(x)
#else
#define FEXP2(x) exp2f(x)
#endif
#if __has_builtin(__builtin_amdgcn_logf)
#define FLOG2(x) __builtin_amdgcn_logf(x)
#else
#define FLOG2(x) log2f(x)
#endif

__device__ __forceinline__ int exp_of(float x) {           // floor(log2(x)), x normal >0
    return ((__float_as_int(x) >> 23) & 255) - 127;
}
__device__ __forceinline__ float pow2i(int e) {            // 2^e, e in [-126,127]
    return __int_as_float((e + 127) << 23);
}
__device__ __forceinline__ unsigned short f2bf_rne(float x) {
    unsigned u = __float_as_uint(x);
    u += 0x7fffu + ((u >> 16) & 1u);
    return (unsigned short)(u >> 16);
}
__device__ __forceinline__ unsigned cvtpk_bf16(float lo, float hi) {
    unsigned r;
    asm("v_cvt_pk_bf16_f32 %0, %1, %2" : "=v"(r) : "v"(lo), "v"(hi));
    return r;
}
__device__ __forceinline__ void xswap32(unsigned &a, unsigned &b) {
#if __has_builtin(__builtin_amdgcn_permlane32_swap)
    auto r = __builtin_amdgcn_permlane32_swap(a, b, false, false);
    a = r[0]; b = r[1];
#else
    unsigned pa = (unsigned)__shfl_xor((int)a, 32);
    unsigned pb = (unsigned)__shfl_xor((int)b, 32);
    bool hb = (threadIdx.x & 32) != 0;
    unsigned na = hb ? pb : a;
    unsigned nb = hb ? b : pa;
    a = na; b = nb;
#endif
}
// D-layout f32[16] -> B-operand fragments (validated r4-r11)
__device__ __forceinline__ void packDtoB(const float* W, bf16x8 &B1, bf16x8 &B2) {
    unsigned pk[8];
#pragma unroll
    for (int q = 0; q < 8; ++q) pk[q] = cvtpk_bf16(W[2 * q], W[2 * q + 1]);
    xswap32(pk[0], pk[2]); xswap32(pk[1], pk[3]);
    xswap32(pk[4], pk[6]); xswap32(pk[5], pk[7]);
    B1 = __builtin_bit_cast(bf16x8, u32x4{pk[0], pk[1], pk[2], pk[3]});
    B2 = __builtin_bit_cast(bf16x8, u32x4{pk[4], pk[5], pk[6], pk[7]});
}
__device__ __forceinline__ void renorm16(float* W, float &Sacc) {
    float m = W[0];
#pragma unroll
    for (int r = 1; r < 16; ++r) m = fmaxf(m, W[r]);
#pragma unroll
    for (int sh = 1; sh <= 32; sh <<= 1) m = fmaxf(m, __shfl_xor(m, sh));
    int g = exp_of(m);
    float iv = pow2i(-g);
#pragma unroll
    for (int r = 0; r < 16; ++r) W[r] *= iv;
    Sacc += (float)g;
}

__global__ __launch_bounds__(512)
void asg_scan(const float* __restrict__ inp, const float* __restrict__ tr,
              const int* __restrict__ tg, float* __restrict__ ws)
{
    const int tid = threadIdx.x;
    const int bid = blockIdx.x;
    // wave id in SGPR: makes all t-derived row bases provably wave-uniform ->
    // SALU addressing + global_load(saddr+voffset), freeing ~5 VALU per load.
    const int wv  = __builtin_amdgcn_readfirstlane(tid >> 6);

    __shared__ unsigned am[NSEG][32][20];     // bf16-packed segment matrices
    __shared__ float uring[NSEG][8][32];
    __shared__ float scl[NSEG];

    if (bid >= 128) {
        // ============ DENOMINATOR: 8 segment transfer matrices / batch =======
        const int lane = tid & 63;
        const int col  = lane & 31;
        const int hi   = lane >> 5;
        const int b    = bid - 128;
        const size_t BC = (size_t)Bn * Cn;

        // E in bf16 A-fragments (validated r4)
        unsigned aw[8];
#pragma unroll
        for (int p = 0; p < 8; ++p) {
            int kb = (p >> 2) * 16 + 8 * hi + (p & 3) * 2;
            unsigned short lo = 0, hh = 0;
            if (col < Cn) {
                if (kb < Cn)     lo = f2bf_rne(FEXP2(LOG2E_F * tr[(1 + col) * Cn + kb]));
                if (kb + 1 < Cn) hh = f2bf_rne(FEXP2(LOG2E_F * tr[(1 + col) * Cn + kb + 1]));
            }
            aw[p] = (unsigned)lo | ((unsigned)hh << 16);
        }
        const bf16x8 A1 = __builtin_bit_cast(bf16x8, u32x4{aw[0], aw[1], aw[2], aw[3]});
        const bf16x8 A2 = __builtin_bit_cast(bf16x8, u32x4{aw[4], aw[5], aw[6], aw[7]});

        f32x16 z;
#pragma unroll
        for (int r = 0; r < 16; ++r) z[r] = 0.f;

        const int start = 1 + SEGL * wv;
        const int cnt   = min(SEGL, Tn - start);           // 250 ... 249

        const int cofs = min(col, Cn - 1);                 // per-lane (VGPR)
        const float* bbase = inp + (size_t)b * Cn;         // uniform
        auto ldrow = [&](int t) {                          // t uniform -> saddr form
            return (bbase + (size_t)t * BC)[cofs];
        };

        float er[8];
#pragma unroll
        for (int p = 0; p < 8; ++p) er[p] = ldrow(min(start + p, Tn - 1));

        if (lane < 32) {
            uring[wv][0][col] = FEXP2(LOG2E_F * er[0]);
            uring[wv][1][col] = FEXP2(LOG2E_F * er[1]);
        }

        float W[16];                                       // M in D-layout, init I
#pragma unroll
        for (int r = 0; r < 16; ++r) {
            int row = (r & 3) + 8 * (r >> 2) + 4 * hi;
            W[r] = (row == col) ? 1.0f : 0.0f;
        }
        float Sacc = 0.f;

        int s = 0;
        for (; s + 8 <= cnt; s += 8) {
#pragma unroll
            for (int u = 0; u < 8; ++u) {
                er[u] = ldrow(min(start + s + u + 8, Tn - 1));   // prefetch
                float un = FEXP2(LOG2E_F * er[(u + 2) & 7]);     // step s+u+2
                if (lane < 32) uring[wv][(u + 2) & 7][col] = un;
                f32x4 uu0 = *(const f32x4*)&uring[wv][u][4 * hi];
                f32x4 uu1 = *(const f32x4*)&uring[wv][u][8 + 4 * hi];
                f32x4 uu2 = *(const f32x4*)&uring[wv][u][16 + 4 * hi];
                f32x4 uu3 = *(const f32x4*)&uring[wv][u][24 + 4 * hi];
                bf16x8 B1, B2;
                packDtoB(W, B1, B2);
                f32x16 d = __builtin_amdgcn_mfma_f32_32x32x16_bf16(A1, B1, z, 0, 0, 0);
                d = __builtin_amdgcn_mfma_f32_32x32x16_bf16(A2, B2, d, 0, 0, 0);
#pragma unroll
                for (int r = 0; r < 16; ++r) {
                    f32x4 uq = (r < 4) ? uu0 : (r < 8) ? uu1 : (r < 12) ? uu2 : uu3;
                    W[r] = d[r] * uq[r & 3];
                }
                if (u == 7) renorm16(W, Sacc);
            }
        }
        {   // tail: rem = 2 (segs 0-6) or 1 (seg 7); uring slots 0,1 hold s, s+1
            const int rem = cnt - s;
#pragma unroll
            for (int u = 0; u < 2; ++u) {
                if (u < rem) {
                    f32x4 uu0 = *(const f32x4*)&uring[wv][u][4 * hi];
                    f32x4 uu1 = *(const f32x4*)&uring[wv][u][8 + 4 * hi];
                    f32x4 uu2 = *(const f32x4*)&uring[wv][u][16 + 4 * hi];
                    f32x4 uu3 = *(const f32x4*)&uring[wv][u][24 + 4 * hi];
                    bf16x8 B1, B2;
                    packDtoB(W, B1, B2);
                    f32x16 d = __builtin_amdgcn_mfma_f32_32x32x16_bf16(A1, B1, z, 0, 0, 0);
                    d = __builtin_amdgcn_mfma_f32_32x32x16_bf16(A2, B2, d, 0, 0, 0);
#pragma unroll
                    for (int r = 0; r < 16; ++r) {
                        f32x4 uq = (r < 4) ? uu0 : (r < 8) ? uu1 : (r < 12) ? uu2 : uu3;
                        W[r] = d[r] * uq[r & 3];
                    }
                }
            }
            renorm16(W, Sacc);
        }

        // store P_w as packed bf16 (u16 element writes; bit-identical to consume-time RNE)
        {
            unsigned short* s16 = (unsigned short*)am[wv];
#pragma unroll
            for (int r = 0; r < 16; ++r) {
                int row = (r & 3) + 8 * (r >> 2) + 4 * hi;
                s16[row * 40 + col] = f2bf_rne(W[r]);
            }
        }
        if (lane == 0) scl[wv] = Sacc;
        __syncthreads();

        // LDS matrix pair product (bf16 storage): out(D-layout regs) = am[Ls] x am[Rs]
        auto lds_mul = [&](int Ls, int Rs, float* Wo) {
            u32x4 a0 = *(const u32x4*)&am[Ls][col][4 * hi];
            u32x4 a1 = *(const u32x4*)&am[Ls][col][8 + 4 * hi];
            bf16x8 LA1 = __builtin_bit_cast(bf16x8, a0);
            bf16x8 LA2 = __builtin_bit_cast(bf16x8, a1);
            const unsigned short* r16 = (const unsigned short*)am[Rs];
            unsigned pk[8];
#pragma unroll
            for (int q = 0; q < 8; ++q) {
                int ra = ((2 * q) & 3) + 8 * ((2 * q) >> 2) + 4 * hi;
                pk[q] = (unsigned)r16[ra * 40 + col] |
                        ((unsigned)r16[(ra + 1) * 40 + col] << 16);
            }
            xswap32(pk[0], pk[2]); xswap32(pk[1], pk[3]);
            xswap32(pk[4], pk[6]); xswap32(pk[5], pk[7]);
            bf16x8 B1 = __builtin_bit_cast(bf16x8, u32x4{pk[0], pk[1], pk[2], pk[3]});
            bf16x8 B2 = __builtin_bit_cast(bf16x8, u32x4{pk[4], pk[5], pk[6], pk[7]});
            f32x16 d = __builtin_amdgcn_mfma_f32_32x32x16_bf16(LA1, B1, z, 0, 0, 0);
            d = __builtin_amdgcn_mfma_f32_32x32x16_bf16(LA2, B2, d, 0, 0, 0);
#pragma unroll
            for (int r = 0; r < 16; ++r) Wo[r] = d[r];
        };
        auto store_mat = [&](int slot, const float* Wo) {
            unsigned short* s16 = (unsigned short*)am[slot];
#pragma unroll
            for (int r = 0; r < 16; ++r) {
                int row = (r & 3) + 8 * (r >> 2) + 4 * hi;
                s16[row * 40 + col] = f2bf_rne(Wo[r]);
            }
        };

        if (wv < 4) {
            float Wq[16];
            lds_mul(2 * wv + 1, 2 * wv, Wq);
            float Sg = scl[2 * wv] + scl[2 * wv + 1];
            renorm16(Wq, Sg);
            store_mat(2 * wv, Wq);
            if (lane == 0) scl[2 * wv] = Sg;
        }
        __syncthreads();
        if (wv < 2) {
            float Wq[16];
            lds_mul(4 * wv + 2, 4 * wv, Wq);
            float Sg = scl[4 * wv] + scl[4 * wv + 2];
            renorm16(Wq, Sg);
            store_mat(4 * wv, Wq);
            if (lane == 0) scl[4 * wv] = Sg;
        }
        __syncthreads();
        if (wv == 0) {
            float Wq[16];
            lds_mul(4, 0, Wq);
            const float Stot = scl[0] + scl[4];
            float a0v = 0.f;
            if (col < Cn)
                a0v = FEXP2(LOG2E_F * (inp[(size_t)b * Cn + col] + tr[col]));
            float ssum = 0.f;
#pragma unroll
            for (int r = 0; r < 16; ++r) ssum += Wq[r];
            float t = ssum * a0v;
#pragma unroll
            for (int sh = 1; sh <= 32; sh <<= 1) t += __shfl_xor(t, sh);
            if (lane == 0) ws[WS_DEN_F + b] = FLOG2(t) + Stot;
        }
    } else {
        // ==== NUMERATOR: linear, per-lane pow2 scales (r10-validated math),
        //      SALU row addressing ====
        const int nid = bid * 8 + wv;
        const int dir = nid >> 9;
        const int b   = nid & 511;
        const int k   = tid & 63;
        const int* tb = tg + b * Ln;

        const int l0 = 3 * k, l1 = 3 * k + 1, l2 = 3 * k + 2;
        const int t0i = (l0 < Ln) ? tb[l0] : 0;
        const int t1i = (l1 < Ln) ? tb[l1] : 0;
        const int t2i = (l2 < Ln) ? tb[l2] : 0;
        const float S0 = FEXP2(LOG2E_F * tr[(1 + t0i) * Cn + t0i]);
        const float S1 = FEXP2(LOG2E_F * tr[(1 + t1i) * Cn + t1i]);
        const float S2 = FEXP2(LOG2E_F * tr[(1 + t2i) * Cn + t2i]);
        const float M0 = (l0 >= 1 && l0 < Ln)
                         ? FEXP2(LOG2E_F * tr[(1 + t0i) * Cn + tb[l0 - 1]]) : 0.f;
        const float M1 = (l1 < Ln) ? FEXP2(LOG2E_F * tr[(1 + t1i) * Cn + t0i]) : 0.f;
        const float M2 = (l2 < Ln) ? FEXP2(LOG2E_F * tr[(1 + t2i) * Cn + t1i]) : 0.f;

        float w0 = 0.f, w1 = 0.f, w2 = 0.f;
        if (dir == 0) {
            if (k == 0) w0 = FEXP2(LOG2E_F * (tr[t0i] + inp[(size_t)b * Cn + t0i]));
        } else {
            if (k == 49) w2 = 1.f;
        }
        int   sE  = 0;
        float m0x = M0;
        float fdn = 1.f;
        int   pgx = 0, psp = 0;

        const size_t BC = (size_t)Bn * Cn;
        // per-lane gather offsets (VGPR); row base stays uniform (SGPR)
        const int o0 = b * Cn + t0i, o1 = b * Cn + t1i, o2 = b * Cn + t2i;
        const int t0 = dir ? (Tn - 1) : 1;
        const int dt = dir ? -1 : 1;
        const int steps = dir ? 1000 : 999;
        auto ld3 = [&](int t, float& a, float& c, float& e) {  // t uniform
            const float* rp = inp + (size_t)t * BC;
            a = rp[o0]; c = rp[o1]; e = rp[o2];
        };

        float ue0[4], ue1[4], ue2[4], pr0[4], pr1[4], pr2[4];
#pragma unroll
        for (int u = 0; u < 4; ++u) {          // block 0 converted
            float a, c, e;
            ld3(t0 + u * dt, a, c, e);
            ue0[u] = FEXP2(LOG2E_F * a);
            ue1[u] = FEXP2(LOG2E_F * c);
            ue2[u] = FEXP2(LOG2E_F * e);
        }

        for (int s = 0; s < steps; s += 4) {
#pragma unroll
            for (int u = 0; u < 4; ++u)        // load block s+4 (in range both dirs)
                ld3(t0 + (s + 4 + u) * dt, pr0[u], pr1[u], pr2[u]);
#pragma unroll
            for (int u = 0; u < 4; ++u) {
                if (s + u < steps) {
                    if (u == 1) {              // apply pending renorm (measured @u==3)
                        float rs = pow2i(-pgx);
                        w0 *= rs; w1 *= rs; w2 *= rs; sE += pgx;
                        int df = psp - sE;
                        df = max(-126, min(56, df));
                        float fx = pow2i(df);
                        m0x = M0 * fx; fdn = fx;
                    }
                    if (dir == 0) {
                        float sh = __shfl_up(w2, 1);
                        sh = (k == 0) ? 0.f : sh;
                        float nn0 = ue0[u] * fmaf(w0, S0, sh * m0x);
                        float nn1 = ue1[u] * fmaf(w1, S1, w0 * M1);
                        float nn2 = ue2[u] * fmaf(w2, S2, w1 * M2);
                        w0 = nn0; w1 = nn1; w2 = nn2;
                    } else {
                        float q0 = w0 * ue0[u], q1 = w1 * ue1[u], q2 = w2 * ue2[u];
                        float mn = __shfl_down(q0 * M0, 1);
                        w0 = fmaf(q0, S0, q1 * M1);
                        w1 = fmaf(q1, S1, q2 * M2);
                        w2 = fmaf(q2, S2, mn * fdn);
                    }
                    if (u == 3) {
                        float mxn = fmaxf(fmaxf(w0, w1), w2);
                        pgx = (mxn > 0.f) ? exp_of(mxn) : 0;
                        int sp = sE + pgx;
                        psp = dir ? __shfl_down(sp, 1) : __shfl_up(sp, 1);
                    }
                }
            }
#pragma unroll
            for (int u = 0; u < 4; ++u) {      // convert block s+4 (off chain)
                ue0[u] = FEXP2(LOG2E_F * pr0[u]);
                ue1[u] = FEXP2(LOG2E_F * pr1[u]);
                ue2[u] = FEXP2(LOG2E_F * pr2[u]);
            }
        }
        const float fsE = (float)sE;
        const int base = (dir ? WS_NUM_B : WS_NUM_F) + b * 160;
        if (l0 < Ln)     ws[base + l0]     = (w0 > 0.f) ? FLOG2(w0) + fsE : NEGV;
        if (l0 + 1 < Ln) ws[base + l0 + 1] = (w1 > 0.f) ? FLOG2(w1) + fsE : NEGV;
        if (l0 + 2 < Ln) ws[base + l0 + 2] = (w2 > 0.f) ? FLOG2(w2) + fsE : NEGV;
    }
}

__global__ __launch_bounds__(512)
void asg_combine(const float* __restrict__ ws, float* __restrict__ out)
{
    __shared__ float red[512];
    const int b = threadIdx.x;

    const float ld = ws[WS_DEN_F + b];            // log2 domain

    const float* nf = ws + WS_NUM_F + b * 160;
    const float* nb = ws + WS_NUM_B + b * 160;
    float vm2 = -3.0e38f;
    for (int l = 0; l < Ln; ++l) vm2 = fmaxf(vm2, nf[l] + nb[l]);
    float sum2 = 0.f;
    for (int l = 0; l < Ln; ++l) sum2 += FEXP2(nf[l] + nb[l] - vm2);
    float ln = vm2 + FLOG2(sum2);

    red[b] = ld - ln;
    __syncthreads();
    for (int off = 256; off > 0; off >>= 1) {
        if (b < off) red[b] += red[b + off];
        __syncthreads();
    }
    if (b == 0) out[0] = red[0] * (LN2_F / 512.0f);
}

extern "C" void kernel_launch(void* const* d_in, const int* in_sizes, int n_in,
                              void* d_out, int out_size, void* d_ws, size_t ws_size,
                              hipStream_t stream)
{
    const float* inp = (const float*)d_in[0];
    const float* tr  = (const float*)d_in[1];
    const int*   tg  = (const int*)d_in[2];
    float* out = (float*)d_out;
    float* ws  = (float*)d_ws;

    hipLaunchKernelGGL(asg_scan,    dim3(640), dim3(512), 0, stream, inp, tr, tg, ws);
    hipLaunchKernelGGL(asg_combine, dim3(1),   dim3(512), 0, stream, ws, out);
}

// Round 14
// 221.303 us; speedup vs baseline: 1.4780x; 1.1200x over previous
//
#include <hip/hip_runtime.h>

static constexpr int Tn = 2000;
static constexpr int Bn = 512;
static constexpr int Cn = 29;
static constexpr int Ln = 150;
static constexpr float LOG2E_F = 1.4426950408889634f;
static constexpr float LN2_F   = 0.6931471805599453f;
static constexpr float NEGV    = -1e30f;

// workspace layout (floats)
static constexpr int WS_DEN_F = 0;                      // 512 (log2-domain log_den per b)
static constexpr int WS_NUM_F = 2 * 512 * 32;           // 512*160
static constexpr int WS_NUM_B = 2 * 512 * 32 + 512 * 160;

static constexpr int NSEG = 8;                          // den segments per batch
static constexpr int SEGL = 250;                        // steps per segment (last: 249)

typedef float  f32x16 __attribute__((ext_vector_type(16)));
typedef float  f32x4  __attribute__((ext_vector_type(4)));
typedef __bf16 bf16x8 __attribute__((ext_vector_type(8)));
typedef unsigned int u32x4 __attribute__((ext_vector_type(4)));

#if __has_builtin(__builtin_amdgcn_exp2f)
#define FEXP2(x) __builtin_amdgcn_exp2f(x)
#else
#define FEXP2(x) exp2f(x)
#endif
#if __has_builtin(__builtin_amdgcn_logf)
#define FLOG2(x) __builtin_amdgcn_logf(x)
#else
#define FLOG2(x) log2f(x)
#endif

__device__ __forceinline__ int exp_of(float x) {           // floor(log2(x)), x normal >0
    return ((__float_as_int(x) >> 23) & 255) - 127;
}
__device__ __forceinline__ float pow2i(int e) {            // 2^e, e in [-126,127]
    return __int_as_float((e + 127) << 23);
}
__device__ __forceinline__ unsigned short f2bf_rne(float x) {
    unsigned u = __float_as_uint(x);
    u += 0x7fffu + ((u >> 16) & 1u);
    return (unsigned short)(u >> 16);
}
__device__ __forceinline__ unsigned cvtpk_bf16(float lo, float hi) {
    unsigned r;
    asm("v_cvt_pk_bf16_f32 %0, %1, %2" : "=v"(r) : "v"(lo), "v"(hi));
    return r;
}
__device__ __forceinline__ void xswap32(unsigned &a, unsigned &b) {
#if __has_builtin(__builtin_amdgcn_permlane32_swap)
    auto r = __builtin_amdgcn_permlane32_swap(a, b, false, false);
    a = r[0]; b = r[1];
#else
    unsigned pa = (unsigned)__shfl_xor((int)a, 32);
    unsigned pb = (unsigned)__shfl_xor((int)b, 32);
    bool hb = (threadIdx.x & 32) != 0;
    unsigned na = hb ? pb : a;
    unsigned nb = hb ? b : pa;
    a = na; b = nb;
#endif
}
// D-layout f32[16] -> B-operand fragments (validated r4-r12)
__device__ __forceinline__ void packDtoB(const float* W, bf16x8 &B1, bf16x8 &B2) {
    unsigned pk[8];
#pragma unroll
    for (int q = 0; q < 8; ++q) pk[q] = cvtpk_bf16(W[2 * q], W[2 * q + 1]);
    xswap32(pk[0], pk[2]); xswap32(pk[1], pk[3]);
    xswap32(pk[4], pk[6]); xswap32(pk[5], pk[7]);
    B1 = __builtin_bit_cast(bf16x8, u32x4{pk[0], pk[1], pk[2], pk[3]});
    B2 = __builtin_bit_cast(bf16x8, u32x4{pk[4], pk[5], pk[6], pk[7]});
}
__device__ __forceinline__ void renorm16(float* W, float &Sacc) {
    float m = W[0];
#pragma unroll
    for (int r = 1; r < 16; ++r) m = fmaxf(m, W[r]);
#pragma unroll
    for (int sh = 1; sh <= 32; sh <<= 1) m = fmaxf(m, __shfl_xor(m, sh));
    int g = exp_of(m);
    float iv = pow2i(-g);
#pragma unroll
    for (int r = 0; r < 16; ++r) W[r] *= iv;
    Sacc += (float)g;
}

__global__ __launch_bounds__(512)
void asg_scan(const float* __restrict__ inp, const float* __restrict__ tr,
              const int* __restrict__ tg, float* __restrict__ ws)
{
    const int tid = threadIdx.x;
    const int bid = blockIdx.x;
    const int wv  = __builtin_amdgcn_readfirstlane(tid >> 6);   // SGPR wave id

    __shared__ unsigned am[NSEG][32][20];     // bf16-packed segment matrices
    __shared__ float uring[NSEG][8][32];
    __shared__ float scl[NSEG];

    if (bid >= 128) {
        // ============ DENOMINATOR: r12-validated structure (byte-exact) =======
        const int lane = tid & 63;
        const int col  = lane & 31;
        const int hi   = lane >> 5;
        const int b    = bid - 128;
        const size_t BC = (size_t)Bn * Cn;

        unsigned aw[8];
#pragma unroll
        for (int p = 0; p < 8; ++p) {
            int kb = (p >> 2) * 16 + 8 * hi + (p & 3) * 2;
            unsigned short lo = 0, hh = 0;
            if (col < Cn) {
                if (kb < Cn)     lo = f2bf_rne(FEXP2(LOG2E_F * tr[(1 + col) * Cn + kb]));
                if (kb + 1 < Cn) hh = f2bf_rne(FEXP2(LOG2E_F * tr[(1 + col) * Cn + kb + 1]));
            }
            aw[p] = (unsigned)lo | ((unsigned)hh << 16);
        }
        const bf16x8 A1 = __builtin_bit_cast(bf16x8, u32x4{aw[0], aw[1], aw[2], aw[3]});
        const bf16x8 A2 = __builtin_bit_cast(bf16x8, u32x4{aw[4], aw[5], aw[6], aw[7]});

        f32x16 z;
#pragma unroll
        for (int r = 0; r < 16; ++r) z[r] = 0.f;

        const int start = 1 + SEGL * wv;
        const int cnt   = min(SEGL, Tn - start);           // 250 ... 249

        const int cofs = min(col, Cn - 1);
        const float* bbase = inp + (size_t)b * Cn;
        auto ldrow = [&](int t) { return (bbase + (size_t)t * BC)[cofs]; };

        float er[8];
#pragma unroll
        for (int p = 0; p < 8; ++p) er[p] = ldrow(min(start + p, Tn - 1));

        if (lane < 32) {
            uring[wv][0][col] = FEXP2(LOG2E_F * er[0]);
            uring[wv][1][col] = FEXP2(LOG2E_F * er[1]);
        }

        float W[16];                                       // M in D-layout, init I
#pragma unroll
        for (int r = 0; r < 16; ++r) {
            int row = (r & 3) + 8 * (r >> 2) + 4 * hi;
            W[r] = (row == col) ? 1.0f : 0.0f;
        }
        float Sacc = 0.f;

        int s = 0;
        for (; s + 8 <= cnt; s += 8) {
#pragma unroll
            for (int u = 0; u < 8; ++u) {
                er[u] = ldrow(min(start + s + u + 8, Tn - 1));   // prefetch
                float un = FEXP2(LOG2E_F * er[(u + 2) & 7]);     // step s+u+2
                if (lane < 32) uring[wv][(u + 2) & 7][col] = un;
                f32x4 uu0 = *(const f32x4*)&uring[wv][u][4 * hi];
                f32x4 uu1 = *(const f32x4*)&uring[wv][u][8 + 4 * hi];
                f32x4 uu2 = *(const f32x4*)&uring[wv][u][16 + 4 * hi];
                f32x4 uu3 = *(const f32x4*)&uring[wv][u][24 + 4 * hi];
                bf16x8 B1, B2;
                packDtoB(W, B1, B2);
                f32x16 d = __builtin_amdgcn_mfma_f32_32x32x16_bf16(A1, B1, z, 0, 0, 0);
                d = __builtin_amdgcn_mfma_f32_32x32x16_bf16(A2, B2, d, 0, 0, 0);
#pragma unroll
                for (int r = 0; r < 16; ++r) {
                    f32x4 uq = (r < 4) ? uu0 : (r < 8) ? uu1 : (r < 12) ? uu2 : uu3;
                    W[r] = d[r] * uq[r & 3];
                }
                if (u == 7) renorm16(W, Sacc);
            }
        }
        {   // tail: rem = 2 (segs 0-6) or 1 (seg 7); uring slots 0,1 hold s, s+1
            const int rem = cnt - s;
#pragma unroll
            for (int u = 0; u < 2; ++u) {
                if (u < rem) {
                    f32x4 uu0 = *(const f32x4*)&uring[wv][u][4 * hi];
                    f32x4 uu1 = *(const f32x4*)&uring[wv][u][8 + 4 * hi];
                    f32x4 uu2 = *(const f32x4*)&uring[wv][u][16 + 4 * hi];
                    f32x4 uu3 = *(const f32x4*)&uring[wv][u][24 + 4 * hi];
                    bf16x8 B1, B2;
                    packDtoB(W, B1, B2);
                    f32x16 d = __builtin_amdgcn_mfma_f32_32x32x16_bf16(A1, B1, z, 0, 0, 0);
                    d = __builtin_amdgcn_mfma_f32_32x32x16_bf16(A2, B2, d, 0, 0, 0);
#pragma unroll
                    for (int r = 0; r < 16; ++r) {
                        f32x4 uq = (r < 4) ? uu0 : (r < 8) ? uu1 : (r < 12) ? uu2 : uu3;
                        W[r] = d[r] * uq[r & 3];
                    }
                }
            }
            renorm16(W, Sacc);
        }

        // store P_w as packed bf16
        {
            unsigned short* s16 = (unsigned short*)am[wv];
#pragma unroll
            for (int r = 0; r < 16; ++r) {
                int row = (r & 3) + 8 * (r >> 2) + 4 * hi;
                s16[row * 40 + col] = f2bf_rne(W[r]);
            }
        }
        if (lane == 0) scl[wv] = Sacc;
        __syncthreads();

        auto lds_mul = [&](int Ls, int Rs, float* Wo) {
            u32x4 a0 = *(const u32x4*)&am[Ls][col][4 * hi];
            u32x4 a1 = *(const u32x4*)&am[Ls][col][8 + 4 * hi];
            bf16x8 LA1 = __builtin_bit_cast(bf16x8, a0);
            bf16x8 LA2 = __builtin_bit_cast(bf16x8, a1);
            const unsigned short* r16 = (const unsigned short*)am[Rs];
            unsigned pk[8];
#pragma unroll
            for (int q = 0; q < 8; ++q) {
                int ra = ((2 * q) & 3) + 8 * ((2 * q) >> 2) + 4 * hi;
                pk[q] = (unsigned)r16[ra * 40 + col] |
                        ((unsigned)r16[(ra + 1) * 40 + col] << 16);
            }
            xswap32(pk[0], pk[2]); xswap32(pk[1], pk[3]);
            xswap32(pk[4], pk[6]); xswap32(pk[5], pk[7]);
            bf16x8 B1 = __builtin_bit_cast(bf16x8, u32x4{pk[0], pk[1], pk[2], pk[3]});
            bf16x8 B2 = __builtin_bit_cast(bf16x8, u32x4{pk[4], pk[5], pk[6], pk[7]});
            f32x16 d = __builtin_amdgcn_mfma_f32_32x32x16_bf16(LA1, B1, z, 0, 0, 0);
            d = __builtin_amdgcn_mfma_f32_32x32x16_bf16(LA2, B2, d, 0, 0, 0);
#pragma unroll
            for (int r = 0; r < 16; ++r) Wo[r] = d[r];
        };
        auto store_mat = [&](int slot, const float* Wo) {
            unsigned short* s16 = (unsigned short*)am[slot];
#pragma unroll
            for (int r = 0; r < 16; ++r) {
                int row = (r & 3) + 8 * (r >> 2) + 4 * hi;
                s16[row * 40 + col] = f2bf_rne(Wo[r]);
            }
        };

        if (wv < 4) {
            float Wq[16];
            lds_mul(2 * wv + 1, 2 * wv, Wq);
            float Sg = scl[2 * wv] + scl[2 * wv + 1];
            renorm16(Wq, Sg);
            store_mat(2 * wv, Wq);
            if (lane == 0) scl[2 * wv] = Sg;
        }
        __syncthreads();
        if (wv < 2) {
            float Wq[16];
            lds_mul(4 * wv + 2, 4 * wv, Wq);
            float Sg = scl[4 * wv] + scl[4 * wv + 2];
            renorm16(Wq, Sg);
            store_mat(4 * wv, Wq);
            if (lane == 0) scl[4 * wv] = Sg;
        }
        __syncthreads();
        if (wv == 0) {
            float Wq[16];
            lds_mul(4, 0, Wq);
            const float Stot = scl[0] + scl[4];
            float a0v = 0.f;
            if (col < Cn)
                a0v = FEXP2(LOG2E_F * (inp[(size_t)b * Cn + col] + tr[col]));
            float ssum = 0.f;
#pragma unroll
            for (int r = 0; r < 16; ++r) ssum += Wq[r];
            float t = ssum * a0v;
#pragma unroll
            for (int sh = 1; sh <= 32; sh <<= 1) t += __shfl_xor(t, sh);
            if (lane == 0) ws[WS_DEN_F + b] = FLOG2(t) + Stot;
        }
    } else {
        // ==== NUMERATOR: linear, per-lane pow2 scales (r10/r12-validated math);
        //      coalesced row load + 1 exp2 + shfl gathers (bit-identical values) ====
        const int nid = bid * 8 + wv;
        const int dir = nid >> 9;
        const int b   = nid & 511;
        const int k   = tid & 63;
        const int* tb = tg + b * Ln;

        const int l0 = 3 * k, l1 = 3 * k + 1, l2 = 3 * k + 2;
        const int t0i = (l0 < Ln) ? tb[l0] : 0;
        const int t1i = (l1 < Ln) ? tb[l1] : 0;
        const int t2i = (l2 < Ln) ? tb[l2] : 0;
        const float S0 = FEXP2(LOG2E_F * tr[(1 + t0i) * Cn + t0i]);
        const float S1 = FEXP2(LOG2E_F * tr[(1 + t1i) * Cn + t1i]);
        const float S2 = FEXP2(LOG2E_F * tr[(1 + t2i) * Cn + t2i]);
        const float M0 = (l0 >= 1 && l0 < Ln)
                         ? FEXP2(LOG2E_F * tr[(1 + t0i) * Cn + tb[l0 - 1]]) : 0.f;
        const float M1 = (l1 < Ln) ? FEXP2(LOG2E_F * tr[(1 + t1i) * Cn + t0i]) : 0.f;
        const float M2 = (l2 < Ln) ? FEXP2(LOG2E_F * tr[(1 + t2i) * Cn + t1i]) : 0.f;

        float w0 = 0.f, w1 = 0.f, w2 = 0.f;
        if (dir == 0) {
            if (k == 0) w0 = FEXP2(LOG2E_F * (tr[t0i] + inp[(size_t)b * Cn + t0i]));
        } else {
            if (k == 49) w2 = 1.f;
        }
        int   sE  = 0;
        float m0x = M0;
        float fdn = 1.f;
        int   pgx = 0, psp = 0;

        const size_t BC = (size_t)Bn * Cn;
        const int cofs = min(k, Cn - 1);                   // coalesced row element
        const float* bbase = inp + (size_t)b * Cn;
        auto ldrow = [&](int t) { return (bbase + (size_t)t * BC)[cofs]; };
        const int t0 = dir ? (Tn - 1) : 1;
        const int dt = dir ? -1 : 1;
        const int steps = dir ? 1000 : 999;

        float ue0[4], ue1[4], ue2[4], rr[4];
#pragma unroll
        for (int u = 0; u < 4; ++u) {          // block 0: load+convert+gather
            float ux = FEXP2(LOG2E_F * ldrow(t0 + u * dt));
            ue0[u] = __shfl(ux, t0i);
            ue1[u] = __shfl(ux, t1i);
            ue2[u] = __shfl(ux, t2i);
        }

        for (int s = 0; s < steps; s += 4) {
#pragma unroll
            for (int u = 0; u < 4; ++u)        // load block s+4 (in range both dirs)
                rr[u] = ldrow(t0 + (s + 4 + u) * dt);
#pragma unroll
            for (int u = 0; u < 4; ++u) {
                if (s + u < steps) {
                    if (u == 1) {              // apply pending renorm (measured @u==3)
                        float rs = pow2i(-pgx);
                        w0 *= rs; w1 *= rs; w2 *= rs; sE += pgx;
                        int df = psp - sE;
                        df = max(-126, min(56, df));
                        float fx = pow2i(df);
                        m0x = M0 * fx; fdn = fx;
                    }
                    if (dir == 0) {
                        float sh = __shfl_up(w2, 1);
                        sh = (k == 0) ? 0.f : sh;
                        float nn0 = ue0[u] * fmaf(w0, S0, sh * m0x);
                        float nn1 = ue1[u] * fmaf(w1, S1, w0 * M1);
                        float nn2 = ue2[u] * fmaf(w2, S2, w1 * M2);
                        w0 = nn0; w1 = nn1; w2 = nn2;
                    } else {
                        float q0 = w0 * ue0[u], q1 = w1 * ue1[u], q2 = w2 * ue2[u];
                        float mn = __shfl_down(q0 * M0, 1);
                        w0 = fmaf(q0, S0, q1 * M1);
                        w1 = fmaf(q1, S1, q2 * M2);
                        w2 = fmaf(q2, S2, mn * fdn);
                    }
                    if (u == 3) {
                        float mxn = fmaxf(fmaxf(w0, w1), w2);
                        pgx = (mxn > 0.f) ? exp_of(mxn) : 0;
                        int sp = sE + pgx;
                        psp = dir ? __shfl_down(sp, 1) : __shfl_up(sp, 1);
                    }
                }
            }
#pragma unroll
            for (int u = 0; u < 4; ++u) {      // convert+gather block s+4 (off chain)
                float ux = FEXP2(LOG2E_F * rr[u]);
                ue0[u] = __shfl(ux, t0i);
                ue1[u] = __shfl(ux, t1i);
                ue2[u] = __shfl(ux, t2i);
            }
        }
        const float fsE = (float)sE;
        const int base = (dir ? WS_NUM_B : WS_NUM_F) + b * 160;
        if (l0 < Ln)     ws[base + l0]     = (w0 > 0.f) ? FLOG2(w0) + fsE : NEGV;
        if (l0 + 1 < Ln) ws[base + l0 + 1] = (w1 > 0.f) ? FLOG2(w1) + fsE : NEGV;
        if (l0 + 2 < Ln) ws[base + l0 + 2] = (w2 > 0.f) ? FLOG2(w2) + fsE : NEGV;
    }
}

__global__ __launch_bounds__(512)
void asg_combine(const float* __restrict__ ws, float* __restrict__ out)
{
    __shared__ float red[512];
    const int b = threadIdx.x;

    const float ld = ws[WS_DEN_F + b];            // log2 domain

    const float* nf = ws + WS_NUM_F + b * 160;
    const float* nb = ws + WS_NUM_B + b * 160;
    float vm2 = -3.0e38f;
    for (int l = 0; l < Ln; ++l) vm2 = fmaxf(vm2, nf[l] + nb[l]);
    float sum2 = 0.f;
    for (int l = 0; l < Ln; ++l) sum2 += FEXP2(nf[l] + nb[l] - vm2);
    float ln = vm2 + FLOG2(sum2);

    red[b] = ld - ln;
    __syncthreads();
    for (int off = 256; off > 0; off >>= 1) {
        if (b < off) red[b] += red[b + off];
        __syncthreads();
    }
    if (b == 0) out[0] = red[0] * (LN2_F / 512.0f);
}

extern "C" void kernel_launch(void* const* d_in, const int* in_sizes, int n_in,
                              void* d_out, int out_size, void* d_ws, size_t ws_size,
                              hipStream_t stream)
{
    const float* inp = (const float*)d_in[0];
    const float* tr  = (const float*)d_in[1];
    const int*   tg  = (const int*)d_in[2];
    float* out = (float*)d_out;
    float* ws  = (float*)d_ws;

    hipLaunchKernelGGL(asg_scan,    dim3(640), dim3(512), 0, stream, inp, tr, tg, ws);
    hipLaunchKernelGGL(asg_combine, dim3(1),   dim3(512), 0, stream, ws, out);
}

// Round 17
// 219.969 us; speedup vs baseline: 1.4870x; 1.0061x over previous
//
#include <hip/hip_runtime.h>

static constexpr int Tn = 2000;
static constexpr int Bn = 512;
static constexpr int Cn = 29;
static constexpr int Ln = 150;
static constexpr float LOG2E_F = 1.4426950408889634f;
static constexpr float LN2_F   = 0.6931471805599453f;
static constexpr float NEGV    = -1e30f;

// workspace layout (floats)
static constexpr int WS_DEN_F = 0;                      // 512 (log2-domain log_den per b)
static constexpr int WS_NUM_F = 2 * 512 * 32;           // 512*160
static constexpr int WS_NUM_B = 2 * 512 * 32 + 512 * 160;

static constexpr int NSEG = 8;                          // den segments per batch
static constexpr int SEGL = 250;                        // steps per segment (last: 249)

typedef float  f32x16 __attribute__((ext_vector_type(16)));
typedef float  f32x4  __attribute__((ext_vector_type(4)));
typedef float  f32x2  __attribute__((ext_vector_type(2)));
typedef __bf16 bf16x8 __attribute__((ext_vector_type(8)));
typedef unsigned int u32x4 __attribute__((ext_vector_type(4)));

#if __has_builtin(__builtin_amdgcn_exp2f)
#define FEXP2(x) __builtin_amdgcn_exp2f(x)
#else
#define FEXP2(x) exp2f(x)
#endif
#if __has_builtin(__builtin_amdgcn_logf)
#define FLOG2(x) __builtin_amdgcn_logf(x)
#else
#define FLOG2(x) log2f(x)
#endif

__device__ __forceinline__ int exp_of(float x) {           // floor(log2(x)), x normal >0
    return ((__float_as_int(x) >> 23) & 255) - 127;
}
__device__ __forceinline__ float pow2i(int e) {            // 2^e, e in [-126,127]
    return __int_as_float((e + 127) << 23);
}
__device__ __forceinline__ unsigned short f2bf_rne(float x) {
    unsigned u = __float_as_uint(x);
    u += 0x7fffu + ((u >> 16) & 1u);
    return (unsigned short)(u >> 16);
}
__device__ __forceinline__ unsigned cvtpk_bf16(float lo, float hi) {
    unsigned r;
    asm("v_cvt_pk_bf16_f32 %0, %1, %2" : "=v"(r) : "v"(lo), "v"(hi));
    return r;
}
__device__ __forceinline__ void xswap32(unsigned &a, unsigned &b) {
#if __has_builtin(__builtin_amdgcn_permlane32_swap)
    auto r = __builtin_amdgcn_permlane32_swap(a, b, false, false);
    a = r[0]; b = r[1];
#else
    unsigned pa = (unsigned)__shfl_xor((int)a, 32);
    unsigned pb = (unsigned)__shfl_xor((int)b, 32);
    bool hb = (threadIdx.x & 32) != 0;
    unsigned na = hb ? pb : a;
    unsigned nb = hb ? b : pa;
    a = na; b = nb;
#endif
}
// D-layout f32[16] -> B-operand fragments (validated r4-r14)
__device__ __forceinline__ void packDtoB(const float* W, bf16x8 &B1, bf16x8 &B2) {
    unsigned pk[8];
#pragma unroll
    for (int q = 0; q < 8; ++q) pk[q] = cvtpk_bf16(W[2 * q], W[2 * q + 1]);
    xswap32(pk[0], pk[2]); xswap32(pk[1], pk[3]);
    xswap32(pk[4], pk[6]); xswap32(pk[5], pk[7]);
    B1 = __builtin_bit_cast(bf16x8, u32x4{pk[0], pk[1], pk[2], pk[3]});
    B2 = __builtin_bit_cast(bf16x8, u32x4{pk[4], pk[5], pk[6], pk[7]});
}
__device__ __forceinline__ void renorm16(float* W, float &Sacc) {
    float m = W[0];
#pragma unroll
    for (int r = 1; r < 16; ++r) m = fmaxf(m, W[r]);
#pragma unroll
    for (int sh = 1; sh <= 32; sh <<= 1) m = fmaxf(m, __shfl_xor(m, sh));
    int g = exp_of(m);
    float iv = pow2i(-g);
    f32x2 iv2 = {iv, iv};
    f32x2* W2 = (f32x2*)W;
#pragma unroll
    for (int j = 0; j < 8; ++j) W2[j] = W2[j] * iv2;       // v_pk_mul_f32
    Sacc += (float)g;
}

__global__ __launch_bounds__(512)
void asg_scan(const float* __restrict__ inp, const float* __restrict__ tr,
              const int* __restrict__ tg, float* __restrict__ ws)
{
    const int tid = threadIdx.x;
    const int bid = blockIdx.x;
    const int wv  = __builtin_amdgcn_readfirstlane(tid >> 6);   // SGPR wave id

    __shared__ unsigned am[NSEG][32][20];     // bf16-packed segment matrices
    __shared__ float uring[NSEG][8][32];
    __shared__ float scl[NSEG];

    if (bid >= 128) {
        // ============ DENOMINATOR: r12/r14-validated structure ============
        const int lane = tid & 63;
        const int col  = lane & 31;
        const int hi   = lane >> 5;
        const int b    = bid - 128;
        const size_t BC = (size_t)Bn * Cn;

        unsigned aw[8];
#pragma unroll
        for (int p = 0; p < 8; ++p) {
            int kb = (p >> 2) * 16 + 8 * hi + (p & 3) * 2;
            unsigned short lo = 0, hh = 0;
            if (col < Cn) {
                if (kb < Cn)     lo = f2bf_rne(FEXP2(LOG2E_F * tr[(1 + col) * Cn + kb]));
                if (kb + 1 < Cn) hh = f2bf_rne(FEXP2(LOG2E_F * tr[(1 + col) * Cn + kb + 1]));
            }
            aw[p] = (unsigned)lo | ((unsigned)hh << 16);
        }
        const bf16x8 A1 = __builtin_bit_cast(bf16x8, u32x4{aw[0], aw[1], aw[2], aw[3]});
        const bf16x8 A2 = __builtin_bit_cast(bf16x8, u32x4{aw[4], aw[5], aw[6], aw[7]});

        f32x16 z;
#pragma unroll
        for (int r = 0; r < 16; ++r) z[r] = 0.f;

        const int start = 1 + SEGL * wv;
        const int cnt   = min(SEGL, Tn - start);           // 250 ... 249

        const int cofs = min(col, Cn - 1);
        const float* bbase = inp + (size_t)b * Cn;
        auto ldrow = [&](int t) { return (bbase + (size_t)t * BC)[cofs]; };

        float er[8];
#pragma unroll
        for (int p = 0; p < 8; ++p) er[p] = ldrow(min(start + p, Tn - 1));

        if (lane < 32) {
            uring[wv][0][col] = FEXP2(LOG2E_F * er[0]);
            uring[wv][1][col] = FEXP2(LOG2E_F * er[1]);
        }

        float W[16];                                       // M in D-layout, init I
#pragma unroll
        for (int r = 0; r < 16; ++r) {
            int row = (r & 3) + 8 * (r >> 2) + 4 * hi;
            W[r] = (row == col) ? 1.0f : 0.0f;
        }
        float Sacc = 0.f;

        int s = 0;
        for (; s + 8 <= cnt; s += 8) {
#pragma unroll
            for (int u = 0; u < 8; ++u) {
                er[u] = ldrow(min(start + s + u + 8, Tn - 1));   // prefetch
                float un = FEXP2(LOG2E_F * er[(u + 2) & 7]);     // step s+u+2
                if (lane < 32) uring[wv][(u + 2) & 7][col] = un;
                f32x4 uu0 = *(const f32x4*)&uring[wv][u][4 * hi];
                f32x4 uu1 = *(const f32x4*)&uring[wv][u][8 + 4 * hi];
                f32x4 uu2 = *(const f32x4*)&uring[wv][u][16 + 4 * hi];
                f32x4 uu3 = *(const f32x4*)&uring[wv][u][24 + 4 * hi];
                bf16x8 B1, B2;
                packDtoB(W, B1, B2);
                f32x16 d = __builtin_amdgcn_mfma_f32_32x32x16_bf16(A1, B1, z, 0, 0, 0);
                d = __builtin_amdgcn_mfma_f32_32x32x16_bf16(A2, B2, d, 0, 0, 0);
                // W = d o u, pk-paired (pairs (2q,2q+1) share the f32x4 group)
                f32x2* W2 = (f32x2*)W;
                W2[0] = f32x2{d[0],  d[1]}  * f32x2{uu0.x, uu0.y};
                W2[1] = f32x2{d[2],  d[3]}  * f32x2{uu0.z, uu0.w};
                W2[2] = f32x2{d[4],  d[5]}  * f32x2{uu1.x, uu1.y};
                W2[3] = f32x2{d[6],  d[7]}  * f32x2{uu1.z, uu1.w};
                W2[4] = f32x2{d[8],  d[9]}  * f32x2{uu2.x, uu2.y};
                W2[5] = f32x2{d[10], d[11]} * f32x2{uu2.z, uu2.w};
                W2[6] = f32x2{d[12], d[13]} * f32x2{uu3.x, uu3.y};
                W2[7] = f32x2{d[14], d[15]} * f32x2{uu3.z, uu3.w};
                if (u == 7) renorm16(W, Sacc);
            }
        }
        {   // tail: rem = 2 (segs 0-6) or 1 (seg 7); uring slots 0,1 hold s, s+1
            const int rem = cnt - s;
#pragma unroll
            for (int u = 0; u < 2; ++u) {
                if (u < rem) {
                    f32x4 uu0 = *(const f32x4*)&uring[wv][u][4 * hi];
                    f32x4 uu1 = *(const f32x4*)&uring[wv][u][8 + 4 * hi];
                    f32x4 uu2 = *(const f32x4*)&uring[wv][u][16 + 4 * hi];
                    f32x4 uu3 = *(const f32x4*)&uring[wv][u][24 + 4 * hi];
                    bf16x8 B1, B2;
                    packDtoB(W, B1, B2);
                    f32x16 d = __builtin_amdgcn_mfma_f32_32x32x16_bf16(A1, B1, z, 0, 0, 0);
                    d = __builtin_amdgcn_mfma_f32_32x32x16_bf16(A2, B2, d, 0, 0, 0);
#pragma unroll
                    for (int r = 0; r < 16; ++r) {
                        f32x4 uq = (r < 4) ? uu0 : (r < 8) ? uu1 : (r < 12) ? uu2 : uu3;
                        W[r] = d[r] * uq[r & 3];
                    }
                }
            }
            renorm16(W, Sacc);
        }

        // store P_w as packed bf16
        {
            unsigned short* s16 = (unsigned short*)am[wv];
#pragma unroll
            for (int r = 0; r < 16; ++r) {
                int row = (r & 3) + 8 * (r >> 2) + 4 * hi;
                s16[row * 40 + col] = f2bf_rne(W[r]);
            }
        }
        if (lane == 0) scl[wv] = Sacc;
        __syncthreads();

        auto lds_mul = [&](int Ls, int Rs, float* Wo) {
            u32x4 a0 = *(const u32x4*)&am[Ls][col][4 * hi];
            u32x4 a1 = *(const u32x4*)&am[Ls][col][8 + 4 * hi];
            bf16x8 LA1 = __builtin_bit_cast(bf16x8, a0);
            bf16x8 LA2 = __builtin_bit_cast(bf16x8, a1);
            const unsigned short* r16 = (const unsigned short*)am[Rs];
            unsigned pk[8];
#pragma unroll
            for (int q = 0; q < 8; ++q) {
                int ra = ((2 * q) & 3) + 8 * ((2 * q) >> 2) + 4 * hi;
                pk[q] = (unsigned)r16[ra * 40 + col] |
                        ((unsigned)r16[(ra + 1) * 40 + col] << 16);
            }
            xswap32(pk[0], pk[2]); xswap32(pk[1], pk[3]);
            xswap32(pk[4], pk[6]); xswap32(pk[5], pk[7]);
            bf16x8 B1 = __builtin_bit_cast(bf16x8, u32x4{pk[0], pk[1], pk[2], pk[3]});
            bf16x8 B2 = __builtin_bit_cast(bf16x8, u32x4{pk[4], pk[5], pk[6], pk[7]});
            f32x16 d = __builtin_amdgcn_mfma_f32_32x32x16_bf16(LA1, B1, z, 0, 0, 0);
            d = __builtin_amdgcn_mfma_f32_32x32x16_bf16(LA2, B2, d, 0, 0, 0);
#pragma unroll
            for (int r = 0; r < 16; ++r) Wo[r] = d[r];
        };
        auto store_mat = [&](int slot, const float* Wo) {
            unsigned short* s16 = (unsigned short*)am[slot];
#pragma unroll
            for (int r = 0; r < 16; ++r) {
                int row = (r & 3) + 8 * (r >> 2) + 4 * hi;
                s16[row * 40 + col] = f2bf_rne(Wo[r]);
            }
        };

        if (wv < 4) {
            float Wq[16];
            lds_mul(2 * wv + 1, 2 * wv, Wq);
            float Sg = scl[2 * wv] + scl[2 * wv + 1];
            renorm16(Wq, Sg);
            store_mat(2 * wv, Wq);
            if (lane == 0) scl[2 * wv] = Sg;
        }
        __syncthreads();
        if (wv < 2) {
            float Wq[16];
            lds_mul(4 * wv + 2, 4 * wv, Wq);
            float Sg = scl[4 * wv] + scl[4 * wv + 2];
            renorm16(Wq, Sg);
            store_mat(4 * wv, Wq);
            if (lane == 0) scl[4 * wv] = Sg;
        }
        __syncthreads();
        if (wv == 0) {
            float Wq[16];
            lds_mul(4, 0, Wq);
            const float Stot = scl[0] + scl[4];
            float a0v = 0.f;
            if (col < Cn)
                a0v = FEXP2(LOG2E_F * (inp[(size_t)b * Cn + col] + tr[col]));
            float ssum = 0.f;
#pragma unroll
            for (int r = 0; r < 16; ++r) ssum += Wq[r];
            float t = ssum * a0v;
#pragma unroll
            for (int sh = 1; sh <= 32; sh <<= 1) t += __shfl_xor(t, sh);
            if (lane == 0) ws[WS_DEN_F + b] = FLOG2(t) + Stot;
        }
    } else {
        // ==== NUMERATOR: byte-exact r14 (validated) ====
        const int nid = bid * 8 + wv;
        const int dir = nid >> 9;
        const int b   = nid & 511;
        const int k   = tid & 63;
        const int* tb = tg + b * Ln;

        const int l0 = 3 * k, l1 = 3 * k + 1, l2 = 3 * k + 2;
        const int t0i = (l0 < Ln) ? tb[l0] : 0;
        const int t1i = (l1 < Ln) ? tb[l1] : 0;
        const int t2i = (l2 < Ln) ? tb[l2] : 0;
        const float S0 = FEXP2(LOG2E_F * tr[(1 + t0i) * Cn + t0i]);
        const float S1 = FEXP2(LOG2E_F * tr[(1 + t1i) * Cn + t1i]);
        const float S2 = FEXP2(LOG2E_F * tr[(1 + t2i) * Cn + t2i]);
        const float M0 = (l0 >= 1 && l0 < Ln)
                         ? FEXP2(LOG2E_F * tr[(1 + t0i) * Cn + tb[l0 - 1]]) : 0.f;
        const float M1 = (l1 < Ln) ? FEXP2(LOG2E_F * tr[(1 + t1i) * Cn + t0i]) : 0.f;
        const float M2 = (l2 < Ln) ? FEXP2(LOG2E_F * tr[(1 + t2i) * Cn + t1i]) : 0.f;

        float w0 = 0.f, w1 = 0.f, w2 = 0.f;
        if (dir == 0) {
            if (k == 0) w0 = FEXP2(LOG2E_F * (tr[t0i] + inp[(size_t)b * Cn + t0i]));
        } else {
            if (k == 49) w2 = 1.f;
        }
        int   sE  = 0;
        float m0x = M0;
        float fdn = 1.f;
        int   pgx = 0, psp = 0;

        const size_t BC = (size_t)Bn * Cn;
        const int cofs = min(k, Cn - 1);                   // coalesced row element
        const float* bbase = inp + (size_t)b * Cn;
        auto ldrow = [&](int t) { return (bbase + (size_t)t * BC)[cofs]; };
        const int t0 = dir ? (Tn - 1) : 1;
        const int dt = dir ? -1 : 1;
        const int steps = dir ? 1000 : 999;

        float ue0[4], ue1[4], ue2[4], rr[4];
#pragma unroll
        for (int u = 0; u < 4; ++u) {          // block 0: load+convert+gather
            float ux = FEXP2(LOG2E_F * ldrow(t0 + u * dt));
            ue0[u] = __shfl(ux, t0i);
            ue1[u] = __shfl(ux, t1i);
            ue2[u] = __shfl(ux, t2i);
        }

        for (int s = 0; s < steps; s += 4) {
#pragma unroll
            for (int u = 0; u < 4; ++u)        // load block s+4 (in range both dirs)
                rr[u] = ldrow(t0 + (s + 4 + u) * dt);
#pragma unroll
            for (int u = 0; u < 4; ++u) {
                if (s + u < steps) {
                    if (u == 1) {              // apply pending renorm (measured @u==3)
                        float rs = pow2i(-pgx);
                        w0 *= rs; w1 *= rs; w2 *= rs; sE += pgx;
                        int df = psp - sE;
                        df = max(-126, min(56, df));
                        float fx = pow2i(df);
                        m0x = M0 * fx; fdn = fx;
                    }
                    if (dir == 0) {
                        float sh = __shfl_up(w2, 1);
                        sh = (k == 0) ? 0.f : sh;
                        float nn0 = ue0[u] * fmaf(w0, S0, sh * m0x);
                        float nn1 = ue1[u] * fmaf(w1, S1, w0 * M1);
                        float nn2 = ue2[u] * fmaf(w2, S2, w1 * M2);
                        w0 = nn0; w1 = nn1; w2 = nn2;
                    } else {
                        float q0 = w0 * ue0[u], q1 = w1 * ue1[u], q2 = w2 * ue2[u];
                        float mn = __shfl_down(q0 * M0, 1);
                        w0 = fmaf(q0, S0, q1 * M1);
                        w1 = fmaf(q1, S1, q2 * M2);
                        w2 = fmaf(q2, S2, mn * fdn);
                    }
                    if (u == 3) {
                        float mxn = fmaxf(fmaxf(w0, w1), w2);
                        pgx = (mxn > 0.f) ? exp_of(mxn) : 0;
                        int sp = sE + pgx;
                        psp = dir ? __shfl_down(sp, 1) : __shfl_up(sp, 1);
                    }
                }
            }
#pragma unroll
            for (int u = 0; u < 4; ++u) {      // convert+gather block s+4 (off chain)
                float ux = FEXP2(LOG2E_F * rr[u]);
                ue0[u] = __shfl(ux, t0i);
                ue1[u] = __shfl(ux, t1i);
                ue2[u] = __shfl(ux, t2i);
            }
        }
        const float fsE = (float)sE;
        const int base = (dir ? WS_NUM_B : WS_NUM_F) + b * 160;
        if (l0 < Ln)     ws[base + l0]     = (w0 > 0.f) ? FLOG2(w0) + fsE : NEGV;
        if (l0 + 1 < Ln) ws[base + l0 + 1] = (w1 > 0.f) ? FLOG2(w1) + fsE : NEGV;
        if (l0 + 2 < Ln) ws[base + l0 + 2] = (w2 > 0.f) ? FLOG2(w2) + fsE : NEGV;
    }
}

__global__ __launch_bounds__(512)
void asg_combine(const float* __restrict__ ws, float* __restrict__ out)
{
    __shared__ float red[512];
    const int b = threadIdx.x;

    const float ld = ws[WS_DEN_F + b];            // log2 domain

    const float* nf = ws + WS_NUM_F + b * 160;
    const float* nb = ws + WS_NUM_B + b * 160;
    float vm2 = -3.0e38f;
    for (int l = 0; l < Ln; ++l) vm2 = fmaxf(vm2, nf[l] + nb[l]);
    float sum2 = 0.f;
    for (int l = 0; l < Ln; ++l) sum2 += FEXP2(nf[l] + nb[l] - vm2);
    float ln = vm2 + FLOG2(sum2);

    red[b] = ld - ln;
    __syncthreads();
    for (int off = 256; off > 0; off >>= 1) {
        if (b < off) red[b] += red[b + off];
        __syncthreads();
    }
    if (b == 0) out[0] = red[0] * (LN2_F / 512.0f);
}

extern "C" void kernel_launch(void* const* d_in, const int* in_sizes, int n_in,
                              void* d_out, int out_size, void* d_ws, size_t ws_size,
                              hipStream_t stream)
{
    const float* inp = (const float*)d_in[0];
    const float* tr  = (const float*)d_in[1];
    const int*   tg  = (const int*)d_in[2];
    float* out = (float*)d_out;
    float* ws  = (float*)d_ws;

    hipLaunchKernelGGL(asg_scan,    dim3(640), dim3(512), 0, stream, inp, tr, tg, ws);
    hipLaunchKernelGGL(asg_combine, dim3(1),   dim3(512), 0, stream, ws, out);
}